// Round 8
// baseline (3888.776 us; speedup 1.0000x reference)
//
#include <hip/hip_runtime.h>

// ---------------- problem constants ----------------
#define TPB   256
#define NWG   256
#define SEQL  200
#define BATCH 64
#define EDIM  300
#define HDIM  512
#define ODIM  5
#define NROW  (4*HDIM)   // 2048 gate rows

// ---------------- group decomposition ----------------
#define GROUPS 8      // independent batch groups (group = blockIdx & 7)
#define GCUS   32     // CUs per group (j = blockIdx >> 3)
#define GB     8      // batch rows per group
#define UNITS  16     // h units per CU
#define ROWS   64     // gate rows per CU (= UNITS * 4 gates)
#define KSLC   32     // k per kh slice (16 slices)

// ---------------- persist-kernel LDS layout (word offsets) ----------------
// [0..4096)      h tile [512 k][8 b], half-XOR swizzled:
//                phys = 8k + 4*(half ^ ((k>>5)&1)) + (b&3)
// [4096..12864)  ex[64 r][8 b] (r stride 137, b stride 17)
// [12864..15264) embT[300][8] (fallback only)
#define H_WORDS  4096
#define EX_OFF   4096
#define EX_RSTR  137
#define EX_BSTR  17
#define EMB_OFF  (EX_OFF + ROWS*EX_RSTR)     // 12864
#define LDS_WORDS (EMB_OFF + EDIM*GB)        // 15264 words
#define LDS_BYTES 83968                      // padded -> 1 wg/CU

#define HSLOT_WORDS (GROUPS * H_WORDS)       // 32768 floats = 128 KiB / slot
#define HSLOT_BYTES (HSLOT_WORDS * 4)

// ---------------- precompute-kernel LDS ----------------
#define ESTR 308
#define PRE_LDS_BYTES (BATCH * ESTR * 4)     // 78848 B

#define GATES_FLOATS ((size_t)SEQL * NROW * BATCH)   // 104.9 MB

__device__ __forceinline__ float fast_sigmoid(float x) {
    return 1.0f / (1.0f + __expf(-x));
}
__device__ __forceinline__ float fast_tanh(float x) {
    return 2.0f / (1.0f + __expf(-2.0f * x)) - 1.0f;
}

// ============================================================================
// Precompute: gates[s][octet g][row][8] = (x_s @ W_ih^T) for batch 8g..8g+7
// GROUP-MAJOR layout so the persist kernel's per-CU read is 4x512B contiguous.
// ============================================================================
extern "C" __global__ void __launch_bounds__(256, 1)
lstm_pre(const int* __restrict__ x, const float* __restrict__ emb,
         const float* __restrict__ W_ih, float* __restrict__ gates)
{
    extern __shared__ float embs[];
    const int tid = threadIdx.x;
    const int s   = blockIdx.x >> 3;
    const int rb  = blockIdx.x & 7;

    for (int i = tid; i < BATCH * 75; i += 256) {
        int b = i / 75, jj = i - b * 75;
        int row = x[b * SEQL + s];
        float4 v = ((const float4*)(emb + (size_t)row * EDIM))[jj];
        *(float4*)&embs[b * ESTR + 4 * jj] = v;
    }
    __syncthreads();

    const int bi = tid >> 5;      // batch octet = group
    const int ri = tid & 31;
    const int row0 = rb * 256 + ri * 8;
    const float* wp = W_ih + (size_t)row0 * EDIM;

    float acc[8][8];
#pragma unroll
    for (int a = 0; a < 8; a++)
#pragma unroll
        for (int b = 0; b < 8; b++) acc[a][b] = 0.0f;

    for (int t2 = 0; t2 < 75; t2++) {
        float4 w[8], e[8];
#pragma unroll
        for (int rr = 0; rr < 8; rr++)
            w[rr] = *(const float4*)(wp + rr * EDIM + 4 * t2);
#pragma unroll
        for (int bb = 0; bb < 8; bb++)
            e[bb] = *(const float4*)&embs[(bi * 8 + bb) * ESTR + 4 * t2];
#pragma unroll
        for (int rr = 0; rr < 8; rr++)
#pragma unroll
            for (int bb = 0; bb < 8; bb++) {
                acc[rr][bb] = fmaf(w[rr].x, e[bb].x, acc[rr][bb]);
                acc[rr][bb] = fmaf(w[rr].y, e[bb].y, acc[rr][bb]);
                acc[rr][bb] = fmaf(w[rr].z, e[bb].z, acc[rr][bb]);
                acc[rr][bb] = fmaf(w[rr].w, e[bb].w, acc[rr][bb]);
            }
    }
    // gates[((s*8 + g)*2048 + row)*8 + b]
#pragma unroll
    for (int rr = 0; rr < 8; rr++) {
        float* dst = gates + (((size_t)s * 8 + bi) * NROW + row0 + rr) * 8;
        *(float4*)dst       = make_float4(acc[rr][0], acc[rr][1], acc[rr][2], acc[rr][3]);
        *(float4*)(dst + 4) = make_float4(acc[rr][4], acc[rr][5], acc[rr][6], acc[rr][7]);
    }
}

// ============================================================================
// Persistent LSTM, 8 independent batch-groups of 32 CUs.
// Group g = blockIdx&7 owns batch rows 8g..8g+7; CU j = blockIdx>>3 owns
// h-units 16j..16j+15 (x4 gates). Pass B runs UNCONDITIONALLY (h slot 0 is
// pre-zeroed) and W_hh VGPRs are pinned with an opaque asm barrier so the
// compiler cannot re-load them per step (round-7 bug: VGPR 80, FETCH 2.7GB).
// ============================================================================
extern "C" __global__ void __launch_bounds__(TPB, 1)
lstm_persist(const int* __restrict__ x, const float* __restrict__ emb,
             const float* __restrict__ W_ih, const float* __restrict__ W_hh,
             const float* __restrict__ b_ih, const float* __restrict__ b_hh,
             const float* __restrict__ gates,   // may be null
             float* __restrict__ hrot,          // rot_n slots of [8 grp][512][8]
             int rot_n,
             unsigned int* __restrict__ flags)  // [256] = [grp][32], memset 0
{
    extern __shared__ float lds[];
    const int tid = threadIdx.x;
    const int g   = blockIdx.x & 7;
    const int j   = blockIdx.x >> 3;
    const bool pre = (gates != nullptr);

    const int rq = tid & 15;      // rows 4rq..4rq+3 (r = gate*16+u)
    const int kh = tid >> 4;      // k in [32kh, 32kh+32)

    // ---- W_hh slice -> 128 VGPRs ----
    float4 w4[4][8];
#pragma unroll
    for (int p = 0; p < 4; p++) {
        const int r = 4 * rq + p;
        const size_t R = (size_t)((r >> 4) * HDIM + UNITS * j + (r & 15));
        const float* wp = W_hh + R * HDIM + KSLC * kh;
#pragma unroll
        for (int kq = 0; kq < 8; kq++) w4[p][kq] = *(const float4*)(wp + 4 * kq);
    }
    // Opaque pin: values now "come from" the asm -> cannot be rematerialized
    // by re-loading W_hh inside the step loop.
#pragma unroll
    for (int p = 0; p < 4; p++)
#pragma unroll
        for (int kq = 0; kq < 8; kq++)
            asm volatile("" : "+v"(w4[p][kq].x), "+v"(w4[p][kq].y),
                             "+v"(w4[p][kq].z), "+v"(w4[p][kq].w));

    // cell role: tid<128 owns (u = tid>>3, b = tid&7)
    const int cu = tid >> 3;
    const int cbb = tid & 7;
    float bias4[4];
#pragma unroll
    for (int gt = 0; gt < 4; gt++) {
        int R = gt * HDIM + UNITS * j + (cu & 15);
        bias4[gt] = b_ih[R] + b_hh[R];
    }
    float c_reg = 0.0f;

    const int sw = 4 * (kh & 1);  // pass-B half-XOR select

    int rbuf = 0, wbuf = 1;
    unsigned int* const myflags = flags + 32 * g;
    __syncthreads();

    for (int s = 0; s < SEQL; s++) {
        // ---- (0) prefetch input-proj gates: 4 x 512B contiguous per CU ----
        float gp[4] = {0.f, 0.f, 0.f, 0.f};
        if (pre && tid < 128) {
            const float* gbase = gates + (((size_t)s * 8 + g) * NROW + UNITS * j) * 8;
#pragma unroll
            for (int gt = 0; gt < 4; gt++)
                gp[gt] = gbase[(size_t)gt * (HDIM * 8) + tid];
        }

        float acc[4][8];
#pragma unroll
        for (int p = 0; p < 4; p++)
#pragma unroll
            for (int b = 0; b < 8; b++) acc[p][b] = 0.f;

        // ---- (1) fallback pass A (cold path; pre-path skips) ----
        if (!pre) {
            for (int i = tid; i < EDIM * GB; i += TPB) {
                int e = i >> 3, b = i & 7;
                int row = x[(GB * g + b) * SEQL + s];
                lds[EMB_OFF + e * 8 + b] = emb[(size_t)row * EDIM + e];
            }
            __syncthreads();
            if (kh < 15) {
                for (int e = 20 * kh; e < 20 * kh + 20; e++) {
                    float4 e0 = *(const float4*)&lds[EMB_OFF + e * 8];
                    float4 e1 = *(const float4*)&lds[EMB_OFF + e * 8 + 4];
#pragma unroll
                    for (int p = 0; p < 4; p++) {
                        const int r = 4 * rq + p;
                        const size_t R = (size_t)((r >> 4) * HDIM + UNITS * j + (r & 15));
                        float wc = W_ih[R * EDIM + e];
                        acc[p][0] = fmaf(wc, e0.x, acc[p][0]);
                        acc[p][1] = fmaf(wc, e0.y, acc[p][1]);
                        acc[p][2] = fmaf(wc, e0.z, acc[p][2]);
                        acc[p][3] = fmaf(wc, e0.w, acc[p][3]);
                        acc[p][4] = fmaf(wc, e1.x, acc[p][4]);
                        acc[p][5] = fmaf(wc, e1.y, acc[p][5]);
                        acc[p][6] = fmaf(wc, e1.z, acc[p][6]);
                        acc[p][7] = fmaf(wc, e1.w, acc[p][7]);
                    }
                }
            }
        }

        // ---- (2) group barrier: 32 flags, one per lane (skip at s=0) ----
        if (s) {
            if (tid < 32) {
                const unsigned tgt = (unsigned)s;
                while (__hip_atomic_load(myflags + tid, __ATOMIC_RELAXED,
                                         __HIP_MEMORY_SCOPE_AGENT) < tgt)
                    __builtin_amdgcn_s_sleep(1);
                __builtin_amdgcn_fence(__ATOMIC_ACQUIRE, "agent");
            }
            __syncthreads();
        }

        // ---- (3) stage h tile (16 KB): 4 loads + 4 swizzled LDS writes ----
        // s=0 reads the pre-zeroed slot 0 -> h_prev = 0 (matches reference).
        {
            const float* hs = hrot + (size_t)rbuf * HSLOT_WORDS + (size_t)g * H_WORDS;
            float4 hv[4];
#pragma unroll
            for (int u = 0; u < 4; u++)
                hv[u] = *(const float4*)(hs + 4 * (tid + 256 * u));
#pragma unroll
            for (int u = 0; u < 4; u++) {
                const int blk = tid + 256 * u;
                const int k = blk >> 1, hf = blk & 1;
                const int phys = 8 * k + 4 * (hf ^ ((k >> 5) & 1));
                *(float4*)&lds[phys] = hv[u];
            }
        }
        __syncthreads();

        // ---- (4) pass B (UNCONDITIONAL): W_hh regs x h LDS ----
#pragma unroll 8
        for (int kidx = 0; kidx < KSLC; kidx++) {
            const int kb = 256 * kh + 8 * kidx;
            float4 h0 = *(const float4*)&lds[kb + sw];        // b 0-3
            float4 h1 = *(const float4*)&lds[kb + (4 - sw)];  // b 4-7
#pragma unroll
            for (int p = 0; p < 4; p++) {
                const float4 wv = w4[p][kidx >> 2];
                const float wc = (kidx & 3) == 0 ? wv.x : (kidx & 3) == 1 ? wv.y
                               : (kidx & 3) == 2 ? wv.z : wv.w;
                acc[p][0] = fmaf(wc, h0.x, acc[p][0]);
                acc[p][1] = fmaf(wc, h0.y, acc[p][1]);
                acc[p][2] = fmaf(wc, h0.z, acc[p][2]);
                acc[p][3] = fmaf(wc, h0.w, acc[p][3]);
                acc[p][4] = fmaf(wc, h1.x, acc[p][4]);
                acc[p][5] = fmaf(wc, h1.y, acc[p][5]);
                acc[p][6] = fmaf(wc, h1.z, acc[p][6]);
                acc[p][7] = fmaf(wc, h1.w, acc[p][7]);
            }
        }
        __syncthreads();   // h-tile readers done; ex region reusable

        // ---- (5) exchange k-partials: ex[r][b][kh], ~2-way banks ----
#pragma unroll
        for (int p = 0; p < 4; p++) {
            const int base = EX_OFF + (4 * rq + p) * EX_RSTR + kh;
#pragma unroll
            for (int b = 0; b < 8; b++)
                lds[base + b * EX_BSTR] = acc[p][b];
        }
        __syncthreads();

        // ---- (6) cell update (tid<128 owns (u, b)) ----
        if (tid < 128) {
            float gs[4];
#pragma unroll
            for (int gt = 0; gt < 4; gt++) {
                float sum = bias4[gt] + gp[gt];
                const int base = EX_OFF + (gt * 16 + cu) * EX_RSTR + cbb * EX_BSTR;
#pragma unroll
                for (int kk = 0; kk < 16; kk++) sum += lds[base + kk];
                gs[gt] = sum;
            }
            float iv = fast_sigmoid(gs[0]);
            float fv = fast_sigmoid(gs[1]);
            float gv = fast_tanh(gs[2]);
            float ov = fast_sigmoid(gs[3]);
            c_reg = fv * c_reg + iv * gv;
            float hv = ov * fast_tanh(c_reg);
            // plain [512][8] group buffer: word (16j+u)*8 + b = j*128 + tid
            unsigned int* hw = (unsigned int*)(hrot + (size_t)wbuf * HSLOT_WORDS
                                               + (size_t)g * H_WORDS);
            __hip_atomic_store(hw + 128 * j + tid, __float_as_uint(hv),
                               __ATOMIC_RELAXED, __HIP_MEMORY_SCOPE_AGENT);
        }
        __syncthreads();   // all h stores drained (vmcnt 0) before flag release

        if (tid == 0)
            __hip_atomic_store(myflags + j, (unsigned)(s + 1),
                               __ATOMIC_RELEASE, __HIP_MEMORY_SCOPE_AGENT);

        rbuf = wbuf;
        wbuf = (wbuf + 1 == rot_n) ? 0 : wbuf + 1;
    }
}

// FC head + softmax. h final: slot fin, group b>>3, word k*8 + (b&7).
extern "C" __global__ void __launch_bounds__(320)
lstm_epilogue(const float* __restrict__ hrot, int fin,
              const float* __restrict__ W_fc, const float* __restrict__ b_fc,
              float* __restrict__ out)
{
    __shared__ float sl[ODIM * BATCH];
    const int t = threadIdx.x;
    {
        int o = t / BATCH, b = t - o * BATCH;
        const float* hb = hrot + (size_t)fin * HSLOT_WORDS + (size_t)(b >> 3) * H_WORDS;
        const int bc = b & 7;
        float acc = b_fc[o];
        const float4* wv = (const float4*)(W_fc + o * HDIM);
#pragma unroll 8
        for (int k4 = 0; k4 < HDIM / 4; k4++) {
            float4 w = wv[k4];
            const int k0 = 4 * k4;
            acc = fmaf(hb[(k0 + 0) * 8 + bc], w.x, acc);
            acc = fmaf(hb[(k0 + 1) * 8 + bc], w.y, acc);
            acc = fmaf(hb[(k0 + 2) * 8 + bc], w.z, acc);
            acc = fmaf(hb[(k0 + 3) * 8 + bc], w.w, acc);
        }
        sl[o * BATCH + b] = acc;
    }
    __syncthreads();
    if (t < BATCH) {
        float l0 = sl[t], l1 = sl[BATCH + t], l2 = sl[2 * BATCH + t];
        float l3 = sl[3 * BATCH + t], l4 = sl[4 * BATCH + t];
        float m = fmaxf(fmaxf(fmaxf(l0, l1), fmaxf(l2, l3)), l4);
        float e0 = __expf(l0 - m), e1 = __expf(l1 - m), e2 = __expf(l2 - m);
        float e3 = __expf(l3 - m), e4 = __expf(l4 - m);
        float inv = 1.0f / (e0 + e1 + e2 + e3 + e4);
        out[t * ODIM + 0] = e0 * inv;
        out[t * ODIM + 1] = e1 * inv;
        out[t * ODIM + 2] = e2 * inv;
        out[t * ODIM + 3] = e3 * inv;
        out[t * ODIM + 4] = e4 * inv;
    }
}

extern "C" void kernel_launch(void* const* d_in, const int* in_sizes, int n_in,
                              void* d_out, int out_size, void* d_ws, size_t ws_size,
                              hipStream_t stream)
{
    const int*   x    = (const int*)d_in[0];
    const float* emb  = (const float*)d_in[1];
    const float* W_ih = (const float*)d_in[2];
    const float* W_hh = (const float*)d_in[3];
    const float* b_ih = (const float*)d_in[4];
    const float* b_hh = (const float*)d_in[5];
    const float* W_fc = (const float*)d_in[6];
    const float* b_fc = (const float*)d_in[7];
    float* out = (float*)d_out;

    // ws layout: [flags 1KB][gates (optional)][rotating h slots]
    unsigned int* flags = (unsigned int*)d_ws;
    char* p = (char*)d_ws + 1024;
    size_t remain = (ws_size > 1024) ? ws_size - 1024 : 0;
    const size_t gates_bytes = GATES_FLOATS * sizeof(float);
    float* gates = nullptr;
    if (remain >= gates_bytes + 2 * (size_t)HSLOT_BYTES) {
        gates = (float*)p;
        p += gates_bytes;
        remain -= gates_bytes;
    }
    int rot_n = (int)(remain / HSLOT_BYTES);
    if (rot_n > SEQL + 1) rot_n = SEQL + 1;
    if (rot_n < 2) rot_n = 2;
    float* hrot = (float*)p;

    (void)hipMemsetAsync(flags, 0, 1024, stream);
    (void)hipMemsetAsync(hrot, 0, HSLOT_BYTES, stream);   // h_prev = 0 for step 0

    (void)hipFuncSetAttribute((const void*)lstm_persist,
                              hipFuncAttributeMaxDynamicSharedMemorySize, LDS_BYTES);
    if (gates) {
        (void)hipFuncSetAttribute((const void*)lstm_pre,
                                  hipFuncAttributeMaxDynamicSharedMemorySize, PRE_LDS_BYTES);
        lstm_pre<<<SEQL * 8, 256, PRE_LDS_BYTES, stream>>>(x, emb, W_ih, gates);
    }

    lstm_persist<<<NWG, TPB, LDS_BYTES, stream>>>(x, emb, W_ih, W_hh, b_ih, b_hh,
                                                  gates, hrot, rot_n, flags);

    const int fin = SEQL % rot_n;   // slot written at step SEQL-1
    lstm_epilogue<<<1, 320, 0, stream>>>(hrot, fin, W_fc, b_fc, out);
}

// Round 9
// 2363.883 us; speedup vs baseline: 1.6451x; 1.6451x over previous
//
#include <hip/hip_runtime.h>

// ---------------- problem constants ----------------
#define TPB   256
#define NWG   256
#define SEQL  200
#define BATCH 64
#define EDIM  300
#define HDIM  512
#define ODIM  5
#define NROW  (4*HDIM)   // 2048 gate rows

// ---------------- group decomposition ----------------
#define GROUPS 8      // independent batch groups (group = blockIdx & 7)
#define GCUS   32     // CUs per group (j = blockIdx >> 3)
#define GB     8      // batch rows per group
#define UNITS  16     // h units per CU
#define ROWS   64     // gate rows per CU (= UNITS * 4 gates)
#define KSLC   32     // k per kh slice (16 slices)

// ---------------- persist-kernel LDS layout (word offsets) ----------------
// [0..4096)      h tile [512 k][8 b], half-XOR swizzled:
//                phys = 8k + 4*(half ^ ((k>>5)&1)) + (b&3)
// [4096..12864)  ex[64 r][8 b] (r stride 137, b stride 17)
// [12864..15264) embT[300][8] (fallback only)
#define H_WORDS  4096
#define EX_OFF   4096
#define EX_RSTR  137
#define EX_BSTR  17
#define EMB_OFF  (EX_OFF + ROWS*EX_RSTR)     // 12864
#define LDS_WORDS (EMB_OFF + EDIM*GB)        // 15264 words
#define LDS_BYTES 83968                      // padded -> 1 wg/CU

#define HSLOT_WORDS (GROUPS * H_WORDS)       // 32768 floats = 128 KiB / slot
#define HSLOT_BYTES (HSLOT_WORDS * 4)

// ---------------- precompute-kernel LDS ----------------
#define ESTR 308
#define PRE_LDS_BYTES (BATCH * ESTR * 4)     // 78848 B

#define GATES_FLOATS ((size_t)SEQL * NROW * BATCH)   // 104.9 MB

__device__ __forceinline__ float fast_sigmoid(float x) {
    return 1.0f / (1.0f + __expf(-x));
}
__device__ __forceinline__ float fast_tanh(float x) {
    return 2.0f / (1.0f + __expf(-2.0f * x)) - 1.0f;
}

// ============================================================================
// Precompute: gates[s][octet g][row][8] = (x_s @ W_ih^T) for batch 8g..8g+7
// GROUP-MAJOR layout so the persist kernel's per-CU read is 4x512B contiguous.
// ============================================================================
extern "C" __global__ void __launch_bounds__(256, 1)
lstm_pre(const int* __restrict__ x, const float* __restrict__ emb,
         const float* __restrict__ W_ih, float* __restrict__ gates)
{
    extern __shared__ float embs[];
    const int tid = threadIdx.x;
    const int s   = blockIdx.x >> 3;
    const int rb  = blockIdx.x & 7;

    for (int i = tid; i < BATCH * 75; i += 256) {
        int b = i / 75, jj = i - b * 75;
        int row = x[b * SEQL + s];
        float4 v = ((const float4*)(emb + (size_t)row * EDIM))[jj];
        *(float4*)&embs[b * ESTR + 4 * jj] = v;
    }
    __syncthreads();

    const int bi = tid >> 5;      // batch octet = group
    const int ri = tid & 31;
    const int row0 = rb * 256 + ri * 8;
    const float* wp = W_ih + (size_t)row0 * EDIM;

    float acc[8][8];
#pragma unroll
    for (int a = 0; a < 8; a++)
#pragma unroll
        for (int b = 0; b < 8; b++) acc[a][b] = 0.0f;

    for (int t2 = 0; t2 < 75; t2++) {
        float4 w[8], e[8];
#pragma unroll
        for (int rr = 0; rr < 8; rr++)
            w[rr] = *(const float4*)(wp + rr * EDIM + 4 * t2);
#pragma unroll
        for (int bb = 0; bb < 8; bb++)
            e[bb] = *(const float4*)&embs[(bi * 8 + bb) * ESTR + 4 * t2];
#pragma unroll
        for (int rr = 0; rr < 8; rr++)
#pragma unroll
            for (int bb = 0; bb < 8; bb++) {
                acc[rr][bb] = fmaf(w[rr].x, e[bb].x, acc[rr][bb]);
                acc[rr][bb] = fmaf(w[rr].y, e[bb].y, acc[rr][bb]);
                acc[rr][bb] = fmaf(w[rr].z, e[bb].z, acc[rr][bb]);
                acc[rr][bb] = fmaf(w[rr].w, e[bb].w, acc[rr][bb]);
            }
    }
    // gates[((s*8 + g)*2048 + row)*8 + b]
#pragma unroll
    for (int rr = 0; rr < 8; rr++) {
        float* dst = gates + (((size_t)s * 8 + bi) * NROW + row0 + rr) * 8;
        *(float4*)dst       = make_float4(acc[rr][0], acc[rr][1], acc[rr][2], acc[rr][3]);
        *(float4*)(dst + 4) = make_float4(acc[rr][4], acc[rr][5], acc[rr][6], acc[rr][7]);
    }
}

// ============================================================================
// Persistent LSTM, 8 independent batch-groups of 32 CUs.
// Group g = blockIdx&7 owns batch rows 8g..8g+7; CU j = blockIdx>>3 owns
// h-units 16j..16j+15 (x4 gates). Pass B is FULLY UNROLLED with static
// indices (rule #20: runtime-indexed reg arrays -> scratch; round-8 bug:
// VGPR 76 + 6.5 MB/step scratch traffic). W_hh slice lives in 128 VGPRs.
// ============================================================================
extern "C" __global__ void __launch_bounds__(TPB, 1)
lstm_persist(const int* __restrict__ x, const float* __restrict__ emb,
             const float* __restrict__ W_ih, const float* __restrict__ W_hh,
             const float* __restrict__ b_ih, const float* __restrict__ b_hh,
             const float* __restrict__ gates,   // may be null
             float* __restrict__ hrot,          // rot_n slots of [8 grp][512][8]
             int rot_n,
             unsigned int* __restrict__ flags)  // [256] = [grp][32], memset 0
{
    extern __shared__ float lds[];
    const int tid = threadIdx.x;
    const int g   = blockIdx.x & 7;
    const int j   = blockIdx.x >> 3;
    const bool pre = (gates != nullptr);

    const int rq = tid & 15;      // rows 4rq..4rq+3 (r = gate*16+u)
    const int kh = tid >> 4;      // k in [32kh, 32kh+32)

    // ---- W_hh slice -> 128 VGPRs (all later indexing is compile-time) ----
    float4 w4[4][8];
#pragma unroll
    for (int p = 0; p < 4; p++) {
        const int r = 4 * rq + p;
        const size_t R = (size_t)((r >> 4) * HDIM + UNITS * j + (r & 15));
        const float* wp = W_hh + R * HDIM + KSLC * kh;
#pragma unroll
        for (int kq = 0; kq < 8; kq++) w4[p][kq] = *(const float4*)(wp + 4 * kq);
    }

    // cell role: tid<128 owns (u = tid>>3, b = tid&7)
    const int cu = tid >> 3;
    const int cbb = tid & 7;
    float bias4[4];
#pragma unroll
    for (int gt = 0; gt < 4; gt++) {
        int R = gt * HDIM + UNITS * j + (cu & 15);
        bias4[gt] = b_ih[R] + b_hh[R];
    }
    float c_reg = 0.0f;

    const int sw = 4 * (kh & 1);  // pass-B half-XOR select

    int rbuf = 0, wbuf = 1;
    unsigned int* const myflags = flags + 32 * g;
    __syncthreads();

    for (int s = 0; s < SEQL; s++) {
        // ---- (0) prefetch input-proj gates: 4 x 512B contiguous per CU ----
        float gp[4] = {0.f, 0.f, 0.f, 0.f};
        if (pre && tid < 128) {
            const float* gbase = gates + (((size_t)s * 8 + g) * NROW + UNITS * j) * 8;
#pragma unroll
            for (int gt = 0; gt < 4; gt++)
                gp[gt] = gbase[(size_t)gt * (HDIM * 8) + tid];
        }

        float acc[4][8];
#pragma unroll
        for (int p = 0; p < 4; p++)
#pragma unroll
            for (int b = 0; b < 8; b++) acc[p][b] = 0.f;

        // ---- (1) fallback pass A (cold path; pre-path skips) ----
        if (!pre) {
            for (int i = tid; i < EDIM * GB; i += TPB) {
                int e = i >> 3, b = i & 7;
                int row = x[(GB * g + b) * SEQL + s];
                lds[EMB_OFF + e * 8 + b] = emb[(size_t)row * EDIM + e];
            }
            __syncthreads();
            if (kh < 15) {
                for (int e = 20 * kh; e < 20 * kh + 20; e++) {
                    float4 e0 = *(const float4*)&lds[EMB_OFF + e * 8];
                    float4 e1 = *(const float4*)&lds[EMB_OFF + e * 8 + 4];
#pragma unroll
                    for (int p = 0; p < 4; p++) {
                        const int r = 4 * rq + p;
                        const size_t R = (size_t)((r >> 4) * HDIM + UNITS * j + (r & 15));
                        float wc = W_ih[R * EDIM + e];
                        acc[p][0] = fmaf(wc, e0.x, acc[p][0]);
                        acc[p][1] = fmaf(wc, e0.y, acc[p][1]);
                        acc[p][2] = fmaf(wc, e0.z, acc[p][2]);
                        acc[p][3] = fmaf(wc, e0.w, acc[p][3]);
                        acc[p][4] = fmaf(wc, e1.x, acc[p][4]);
                        acc[p][5] = fmaf(wc, e1.y, acc[p][5]);
                        acc[p][6] = fmaf(wc, e1.z, acc[p][6]);
                        acc[p][7] = fmaf(wc, e1.w, acc[p][7]);
                    }
                }
            }
        }

        // ---- (2) group barrier: 32 flags, one per lane (skip at s=0) ----
        if (s) {
            if (tid < 32) {
                const unsigned tgt = (unsigned)s;
                while (__hip_atomic_load(myflags + tid, __ATOMIC_RELAXED,
                                         __HIP_MEMORY_SCOPE_AGENT) < tgt)
                    __builtin_amdgcn_s_sleep(1);
                __builtin_amdgcn_fence(__ATOMIC_ACQUIRE, "agent");
            }
            __syncthreads();
        }

        // ---- (3) stage h tile (16 KB): 4 loads + 4 swizzled LDS writes ----
        // s=0 reads the pre-zeroed slot 0 -> h_prev = 0 (matches reference).
        {
            const float* hs = hrot + (size_t)rbuf * HSLOT_WORDS + (size_t)g * H_WORDS;
            float4 hv[4];
#pragma unroll
            for (int u = 0; u < 4; u++)
                hv[u] = *(const float4*)(hs + 4 * (tid + 256 * u));
#pragma unroll
            for (int u = 0; u < 4; u++) {
                const int blk = tid + 256 * u;
                const int k = blk >> 1, hf = blk & 1;
                const int phys = 8 * k + 4 * (hf ^ ((k >> 5) & 1));
                *(float4*)&lds[phys] = hv[u];
            }
        }
        __syncthreads();

        // ---- (4) pass B: FULLY static unroll; W_hh regs x h LDS ----
#pragma unroll
        for (int kq = 0; kq < 8; kq++) {
#pragma unroll
            for (int ki = 0; ki < 4; ki++) {
                const int kb = 256 * kh + 8 * (4 * kq + ki);
                float4 h0 = *(const float4*)&lds[kb + sw];        // b 0-3
                float4 h1 = *(const float4*)&lds[kb + (4 - sw)];  // b 4-7
#pragma unroll
                for (int p = 0; p < 4; p++) {
                    const float4 wv = w4[p][kq];
                    const float wc = ki == 0 ? wv.x : ki == 1 ? wv.y
                                   : ki == 2 ? wv.z : wv.w;
                    acc[p][0] = fmaf(wc, h0.x, acc[p][0]);
                    acc[p][1] = fmaf(wc, h0.y, acc[p][1]);
                    acc[p][2] = fmaf(wc, h0.z, acc[p][2]);
                    acc[p][3] = fmaf(wc, h0.w, acc[p][3]);
                    acc[p][4] = fmaf(wc, h1.x, acc[p][4]);
                    acc[p][5] = fmaf(wc, h1.y, acc[p][5]);
                    acc[p][6] = fmaf(wc, h1.z, acc[p][6]);
                    acc[p][7] = fmaf(wc, h1.w, acc[p][7]);
                }
            }
        }
        __syncthreads();   // h-tile readers done; ex region reusable

        // ---- (5) exchange k-partials: ex[r][b][kh], ~2-way banks ----
#pragma unroll
        for (int p = 0; p < 4; p++) {
            const int base = EX_OFF + (4 * rq + p) * EX_RSTR + kh;
#pragma unroll
            for (int b = 0; b < 8; b++)
                lds[base + b * EX_BSTR] = acc[p][b];
        }
        __syncthreads();

        // ---- (6) cell update (tid<128 owns (u, b)) ----
        if (tid < 128) {
            float gs[4];
#pragma unroll
            for (int gt = 0; gt < 4; gt++) {
                float sum = bias4[gt] + gp[gt];
                const int base = EX_OFF + (gt * 16 + cu) * EX_RSTR + cbb * EX_BSTR;
#pragma unroll
                for (int kk = 0; kk < 16; kk++) sum += lds[base + kk];
                gs[gt] = sum;
            }
            float iv = fast_sigmoid(gs[0]);
            float fv = fast_sigmoid(gs[1]);
            float gv = fast_tanh(gs[2]);
            float ov = fast_sigmoid(gs[3]);
            c_reg = fv * c_reg + iv * gv;
            float hv = ov * fast_tanh(c_reg);
            // plain [512][8] group buffer: word (16j+u)*8 + b = j*128 + tid
            unsigned int* hw = (unsigned int*)(hrot + (size_t)wbuf * HSLOT_WORDS
                                               + (size_t)g * H_WORDS);
            __hip_atomic_store(hw + 128 * j + tid, __float_as_uint(hv),
                               __ATOMIC_RELAXED, __HIP_MEMORY_SCOPE_AGENT);
        }
        __syncthreads();   // all h stores drained (vmcnt 0) before flag release

        if (tid == 0)
            __hip_atomic_store(myflags + j, (unsigned)(s + 1),
                               __ATOMIC_RELEASE, __HIP_MEMORY_SCOPE_AGENT);

        rbuf = wbuf;
        wbuf = (wbuf + 1 == rot_n) ? 0 : wbuf + 1;
    }
}

// FC head + softmax. h final: slot fin, group b>>3, word k*8 + (b&7).
extern "C" __global__ void __launch_bounds__(320)
lstm_epilogue(const float* __restrict__ hrot, int fin,
              const float* __restrict__ W_fc, const float* __restrict__ b_fc,
              float* __restrict__ out)
{
    __shared__ float sl[ODIM * BATCH];
    const int t = threadIdx.x;
    {
        int o = t / BATCH, b = t - o * BATCH;
        const float* hb = hrot + (size_t)fin * HSLOT_WORDS + (size_t)(b >> 3) * H_WORDS;
        const int bc = b & 7;
        float acc = b_fc[o];
        const float4* wv = (const float4*)(W_fc + o * HDIM);
#pragma unroll 8
        for (int k4 = 0; k4 < HDIM / 4; k4++) {
            float4 w = wv[k4];
            const int k0 = 4 * k4;
            acc = fmaf(hb[(k0 + 0) * 8 + bc], w.x, acc);
            acc = fmaf(hb[(k0 + 1) * 8 + bc], w.y, acc);
            acc = fmaf(hb[(k0 + 2) * 8 + bc], w.z, acc);
            acc = fmaf(hb[(k0 + 3) * 8 + bc], w.w, acc);
        }
        sl[o * BATCH + b] = acc;
    }
    __syncthreads();
    if (t < BATCH) {
        float l0 = sl[t], l1 = sl[BATCH + t], l2 = sl[2 * BATCH + t];
        float l3 = sl[3 * BATCH + t], l4 = sl[4 * BATCH + t];
        float m = fmaxf(fmaxf(fmaxf(l0, l1), fmaxf(l2, l3)), l4);
        float e0 = __expf(l0 - m), e1 = __expf(l1 - m), e2 = __expf(l2 - m);
        float e3 = __expf(l3 - m), e4 = __expf(l4 - m);
        float inv = 1.0f / (e0 + e1 + e2 + e3 + e4);
        out[t * ODIM + 0] = e0 * inv;
        out[t * ODIM + 1] = e1 * inv;
        out[t * ODIM + 2] = e2 * inv;
        out[t * ODIM + 3] = e3 * inv;
        out[t * ODIM + 4] = e4 * inv;
    }
}

extern "C" void kernel_launch(void* const* d_in, const int* in_sizes, int n_in,
                              void* d_out, int out_size, void* d_ws, size_t ws_size,
                              hipStream_t stream)
{
    const int*   x    = (const int*)d_in[0];
    const float* emb  = (const float*)d_in[1];
    const float* W_ih = (const float*)d_in[2];
    const float* W_hh = (const float*)d_in[3];
    const float* b_ih = (const float*)d_in[4];
    const float* b_hh = (const float*)d_in[5];
    const float* W_fc = (const float*)d_in[6];
    const float* b_fc = (const float*)d_in[7];
    float* out = (float*)d_out;

    // ws layout: [flags 1KB][gates (optional)][rotating h slots]
    unsigned int* flags = (unsigned int*)d_ws;
    char* p = (char*)d_ws + 1024;
    size_t remain = (ws_size > 1024) ? ws_size - 1024 : 0;
    const size_t gates_bytes = GATES_FLOATS * sizeof(float);
    float* gates = nullptr;
    if (remain >= gates_bytes + 2 * (size_t)HSLOT_BYTES) {
        gates = (float*)p;
        p += gates_bytes;
        remain -= gates_bytes;
    }
    int rot_n = (int)(remain / HSLOT_BYTES);
    if (rot_n > SEQL + 1) rot_n = SEQL + 1;
    if (rot_n < 2) rot_n = 2;
    float* hrot = (float*)p;

    (void)hipMemsetAsync(flags, 0, 1024, stream);
    (void)hipMemsetAsync(hrot, 0, HSLOT_BYTES, stream);   // h_prev = 0 for step 0

    (void)hipFuncSetAttribute((const void*)lstm_persist,
                              hipFuncAttributeMaxDynamicSharedMemorySize, LDS_BYTES);
    if (gates) {
        (void)hipFuncSetAttribute((const void*)lstm_pre,
                                  hipFuncAttributeMaxDynamicSharedMemorySize, PRE_LDS_BYTES);
        lstm_pre<<<SEQL * 8, 256, PRE_LDS_BYTES, stream>>>(x, emb, W_ih, gates);
    }

    lstm_persist<<<NWG, TPB, LDS_BYTES, stream>>>(x, emb, W_ih, W_hh, b_ih, b_hh,
                                                  gates, hrot, rot_n, flags);

    const int fin = SEQL % rot_n;   // slot written at step SEQL-1
    lstm_epilogue<<<1, 320, 0, stream>>>(hrot, fin, W_fc, b_fc, out);
}

// Round 10
// 1790.419 us; speedup vs baseline: 2.1720x; 1.3203x over previous
//
#include <hip/hip_runtime.h>

// ---------------- problem constants ----------------
#define TPB   256
#define NWG   256
#define SEQL  200
#define BATCH 64
#define EDIM  300
#define HDIM  512
#define ODIM  5
#define NROW  (4*HDIM)   // 2048 gate rows

// ---------------- group decomposition ----------------
#define GROUPS 8      // independent batch groups (group = blockIdx & 7)
#define GCUS   32     // CUs per group (j = blockIdx >> 3)
#define GB     8      // batch rows per group
#define UNITS  16     // h units per CU
#define KSLC   32     // k per kh slice (16 slices)

// ---------------- persist-kernel LDS layout (word offsets) ----------------
// [0..4096)      h tile [512 k][8 b], half-XOR swizzled:
//                phys = 8k + 4*(half ^ ((k>>5)&1)) + (b&3)
// [4096..12864)  ex[64 r][8 b] (r stride 137, b stride 17)
// [12864..15264) embT[300][8] (fallback only)
#define H_WORDS  4096
#define EX_OFF   4096
#define EX_RSTR  137
#define EX_BSTR  17
#define EMB_OFF  (EX_OFF + 64*EX_RSTR)       // 12864
#define LDS_BYTES 83968                      // padded -> 1 wg/CU

// ---------------- tagged h exchange ----------------
// htag[parity][group][4096] : ull = (tag << 32) | f32bits(value)
// value index vi = k*8 + b.  Input for step s: parity s&1, tag == s.
#define HT_GROUP 4096
#define HT_PAR   (GROUPS * HT_GROUP)               // 32768 ull per parity
#define HT_TOTAL (2 * HT_PAR)                      // 65536 ull = 512 KiB
#define HT_BYTES (HT_TOTAL * 8)

// ---------------- precompute-kernel LDS ----------------
#define ESTR 308
#define PRE_LDS_BYTES (BATCH * ESTR * 4)     // 78848 B

#define GATES_FLOATS ((size_t)SEQL * NROW * BATCH)   // 104.9 MB

__device__ __forceinline__ float fast_sigmoid(float x) {
    return 1.0f / (1.0f + __expf(-x));
}
__device__ __forceinline__ float fast_tanh(float x) {
    return 2.0f / (1.0f + __expf(-2.0f * x)) - 1.0f;
}

// ============================================================================
// Precompute: gates[s][octet g][row][8] = (x_s @ W_ih^T) for batch 8g..8g+7
// ============================================================================
extern "C" __global__ void __launch_bounds__(256, 1)
lstm_pre(const int* __restrict__ x, const float* __restrict__ emb,
         const float* __restrict__ W_ih, float* __restrict__ gates)
{
    extern __shared__ float embs[];
    const int tid = threadIdx.x;
    const int s   = blockIdx.x >> 3;
    const int rb  = blockIdx.x & 7;

    for (int i = tid; i < BATCH * 75; i += 256) {
        int b = i / 75, jj = i - b * 75;
        int row = x[b * SEQL + s];
        float4 v = ((const float4*)(emb + (size_t)row * EDIM))[jj];
        *(float4*)&embs[b * ESTR + 4 * jj] = v;
    }
    __syncthreads();

    const int bi = tid >> 5;      // batch octet = group
    const int ri = tid & 31;
    const int row0 = rb * 256 + ri * 8;
    const float* wp = W_ih + (size_t)row0 * EDIM;

    float acc[8][8];
#pragma unroll
    for (int a = 0; a < 8; a++)
#pragma unroll
        for (int b = 0; b < 8; b++) acc[a][b] = 0.0f;

    for (int t2 = 0; t2 < 75; t2++) {
        float4 w[8], e[8];
#pragma unroll
        for (int rr = 0; rr < 8; rr++)
            w[rr] = *(const float4*)(wp + rr * EDIM + 4 * t2);
#pragma unroll
        for (int bb = 0; bb < 8; bb++)
            e[bb] = *(const float4*)&embs[(bi * 8 + bb) * ESTR + 4 * t2];
#pragma unroll
        for (int rr = 0; rr < 8; rr++)
#pragma unroll
            for (int bb = 0; bb < 8; bb++) {
                acc[rr][bb] = fmaf(w[rr].x, e[bb].x, acc[rr][bb]);
                acc[rr][bb] = fmaf(w[rr].y, e[bb].y, acc[rr][bb]);
                acc[rr][bb] = fmaf(w[rr].z, e[bb].z, acc[rr][bb]);
                acc[rr][bb] = fmaf(w[rr].w, e[bb].w, acc[rr][bb]);
            }
    }
#pragma unroll
    for (int rr = 0; rr < 8; rr++) {
        float* dst = gates + (((size_t)s * 8 + bi) * NROW + row0 + rr) * 8;
        *(float4*)dst       = make_float4(acc[rr][0], acc[rr][1], acc[rr][2], acc[rr][3]);
        *(float4*)(dst + 4) = make_float4(acc[rr][4], acc[rr][5], acc[rr][6], acc[rr][7]);
    }
}

// ============================================================================
// Persistent LSTM, 8 independent batch-groups of 32 CUs.
// h exchange is TAGGED: 8B words {tag,value}, parity double-buffered. No
// flags, NO fences — each word self-validates; 8B atomics are single-copy
// atomic at L3. Safety: tag s+2 can only be written after every group member
// completed step s (each stages the full tile), so expected tags never skip.
// ============================================================================
extern "C" __global__ void __launch_bounds__(TPB, 1)
lstm_persist(const int* __restrict__ x, const float* __restrict__ emb,
             const float* __restrict__ W_ih, const float* __restrict__ W_hh,
             const float* __restrict__ b_ih, const float* __restrict__ b_hh,
             const float* __restrict__ gates,      // may be null
             unsigned long long* __restrict__ htag) // [2][8][4096] tagged h
{
    extern __shared__ float lds[];
    const int tid = threadIdx.x;
    const int g   = blockIdx.x & 7;
    const int j   = blockIdx.x >> 3;
    const bool pre = (gates != nullptr);

    const int rq = tid & 15;      // rows 4rq..4rq+3 (r = gate*16+u)
    const int kh = tid >> 4;      // k in [32kh, 32kh+32)

    // ---- W_hh slice -> 128 VGPRs (all indexing compile-time; rule #20) ----
    float4 w4[4][8];
#pragma unroll
    for (int p = 0; p < 4; p++) {
        const int r = 4 * rq + p;
        const size_t R = (size_t)((r >> 4) * HDIM + UNITS * j + (r & 15));
        const float* wp = W_hh + R * HDIM + KSLC * kh;
#pragma unroll
        for (int kq = 0; kq < 8; kq++) w4[p][kq] = *(const float4*)(wp + 4 * kq);
    }

    // cell role: tid<128 owns (u = tid>>3, b = tid&7)
    const int cu = tid >> 3;
    const int cbb = tid & 7;
    float bias4[4];
#pragma unroll
    for (int gt = 0; gt < 4; gt++) {
        int R = gt * HDIM + UNITS * j + (cu & 15);
        bias4[gt] = b_ih[R] + b_hh[R];
    }
    float c_reg = 0.0f;

    const int sw = 4 * (kh & 1);  // pass-B half-XOR select

    unsigned long long* const T0 = htag + (size_t)g * HT_GROUP;            // parity 0
    unsigned long long* const T1 = htag + HT_PAR + (size_t)g * HT_GROUP;   // parity 1

    __syncthreads();

    for (int s = 0; s < SEQL; s++) {
        const unsigned long long* Tin = (s & 1) ? T1 : T0;
        unsigned long long*       Tout = (s & 1) ? T0 : T1;

        // ---- (0) prefetch input-proj gates: 4 x 512B contiguous per CU ----
        float gp[4] = {0.f, 0.f, 0.f, 0.f};
        if (pre && tid < 128) {
            const float* gbase = gates + (((size_t)s * 8 + g) * NROW + UNITS * j) * 8;
#pragma unroll
            for (int gt = 0; gt < 4; gt++)
                gp[gt] = gbase[(size_t)gt * (HDIM * 8) + tid];
        }

        float acc[4][8];
#pragma unroll
        for (int p = 0; p < 4; p++)
#pragma unroll
            for (int b = 0; b < 8; b++) acc[p][b] = 0.f;

        // ---- (1) fallback pass A (cold path; pre-path skips) ----
        if (!pre) {
            for (int i = tid; i < EDIM * GB; i += TPB) {
                int e = i >> 3, b = i & 7;
                int row = x[(GB * g + b) * SEQL + s];
                lds[EMB_OFF + e * 8 + b] = emb[(size_t)row * EDIM + e];
            }
            __syncthreads();
            if (kh < 15) {
                for (int e = 20 * kh; e < 20 * kh + 20; e++) {
                    float4 e0 = *(const float4*)&lds[EMB_OFF + e * 8];
                    float4 e1 = *(const float4*)&lds[EMB_OFF + e * 8 + 4];
#pragma unroll
                    for (int p = 0; p < 4; p++) {
                        const int r = 4 * rq + p;
                        const size_t R = (size_t)((r >> 4) * HDIM + UNITS * j + (r & 15));
                        float wc = W_ih[R * EDIM + e];
                        acc[p][0] = fmaf(wc, e0.x, acc[p][0]);
                        acc[p][1] = fmaf(wc, e0.y, acc[p][1]);
                        acc[p][2] = fmaf(wc, e0.z, acc[p][2]);
                        acc[p][3] = fmaf(wc, e0.w, acc[p][3]);
                        acc[p][4] = fmaf(wc, e1.x, acc[p][4]);
                        acc[p][5] = fmaf(wc, e1.y, acc[p][5]);
                        acc[p][6] = fmaf(wc, e1.z, acc[p][6]);
                        acc[p][7] = fmaf(wc, e1.w, acc[p][7]);
                    }
                }
            }
            __syncthreads();   // embT reads done before h-tile staging below
        }

        // ---- (2) poll-stage tagged h tile: 16 x 8B atomic loads / thread ----
        // Thread's value indices: {4*tid + 1024u + 0..3 : u<4} (full tile).
        {
            const unsigned tag = (unsigned)s;
            unsigned long long d[16];
            for (;;) {
                bool ok = true;
#pragma unroll
                for (int u = 0; u < 4; u++) {
                    const int vi = 4 * tid + 1024 * u;
#pragma unroll
                    for (int q = 0; q < 4; q++)
                        d[4 * u + q] = __hip_atomic_load(Tin + vi + q,
                                                         __ATOMIC_RELAXED,
                                                         __HIP_MEMORY_SCOPE_AGENT);
                }
#pragma unroll
                for (int w = 0; w < 16; w++)
                    ok &= ((unsigned)(d[w] >> 32) == tag);
                if (ok) break;
                __builtin_amdgcn_s_sleep(1);
            }
#pragma unroll
            for (int u = 0; u < 4; u++) {
                float4 hv;
                hv.x = __uint_as_float((unsigned)d[4 * u + 0]);
                hv.y = __uint_as_float((unsigned)d[4 * u + 1]);
                hv.z = __uint_as_float((unsigned)d[4 * u + 2]);
                hv.w = __uint_as_float((unsigned)d[4 * u + 3]);
                const int blk = tid + 256 * u;
                const int k = blk >> 1, hf = blk & 1;
                const int phys = 8 * k + 4 * (hf ^ ((k >> 5) & 1));
                *(float4*)&lds[phys] = hv;
            }
        }
        __syncthreads();

        // ---- (3) pass B: fully static unroll; W_hh regs x h LDS ----
#pragma unroll
        for (int kq = 0; kq < 8; kq++) {
#pragma unroll
            for (int ki = 0; ki < 4; ki++) {
                const int kb = 256 * kh + 8 * (4 * kq + ki);
                float4 h0 = *(const float4*)&lds[kb + sw];        // b 0-3
                float4 h1 = *(const float4*)&lds[kb + (4 - sw)];  // b 4-7
#pragma unroll
                for (int p = 0; p < 4; p++) {
                    const float4 wv = w4[p][kq];
                    const float wc = ki == 0 ? wv.x : ki == 1 ? wv.y
                                   : ki == 2 ? wv.z : wv.w;
                    acc[p][0] = fmaf(wc, h0.x, acc[p][0]);
                    acc[p][1] = fmaf(wc, h0.y, acc[p][1]);
                    acc[p][2] = fmaf(wc, h0.z, acc[p][2]);
                    acc[p][3] = fmaf(wc, h0.w, acc[p][3]);
                    acc[p][4] = fmaf(wc, h1.x, acc[p][4]);
                    acc[p][5] = fmaf(wc, h1.y, acc[p][5]);
                    acc[p][6] = fmaf(wc, h1.z, acc[p][6]);
                    acc[p][7] = fmaf(wc, h1.w, acc[p][7]);
                }
            }
        }
        __syncthreads();   // h-tile readers done; ex region reusable

        // ---- (4) exchange k-partials: ex[r][b][kh], ~2-way banks ----
#pragma unroll
        for (int p = 0; p < 4; p++) {
            const int base = EX_OFF + (4 * rq + p) * EX_RSTR + kh;
#pragma unroll
            for (int b = 0; b < 8; b++)
                lds[base + b * EX_BSTR] = acc[p][b];
        }
        __syncthreads();

        // ---- (5) cell update + tagged store (tid<128 owns (u, b)) ----
        if (tid < 128) {
            float gs[4];
#pragma unroll
            for (int gt = 0; gt < 4; gt++) {
                float sum = bias4[gt] + gp[gt];
                const int base = EX_OFF + (gt * 16 + cu) * EX_RSTR + cbb * EX_BSTR;
#pragma unroll
                for (int kk = 0; kk < 16; kk++) sum += lds[base + kk];
                gs[gt] = sum;
            }
            float iv = fast_sigmoid(gs[0]);
            float fv = fast_sigmoid(gs[1]);
            float gv = fast_tanh(gs[2]);
            float ov = fast_sigmoid(gs[3]);
            c_reg = fv * c_reg + iv * gv;
            float hv = ov * fast_tanh(c_reg);
            // vi = (16j+u)*8 + b = 128j + tid ; tag = s+1
            unsigned long long wword =
                ((unsigned long long)(unsigned)(s + 1) << 32) |
                (unsigned long long)__float_as_uint(hv);
            __hip_atomic_store(Tout + 128 * j + tid, wword,
                               __ATOMIC_RELAXED, __HIP_MEMORY_SCOPE_AGENT);
        }
        // no trailing barrier needed: next step's LDS writes (h tile) are
        // disjoint from ex; ex rewrite at s+1 sits behind two __syncthreads.
    }
}

// FC head + softmax. Final h: parity SEQL&1 = 0, value = lo32 of tagged word.
extern "C" __global__ void __launch_bounds__(320)
lstm_epilogue(const unsigned long long* __restrict__ htag,
              const float* __restrict__ W_fc, const float* __restrict__ b_fc,
              float* __restrict__ out)
{
    __shared__ float sl[ODIM * BATCH];
    const int t = threadIdx.x;
    {
        int o = t / BATCH, b = t - o * BATCH;
        const unsigned long long* hb = htag + (size_t)(b >> 3) * HT_GROUP;
        const int bc = b & 7;
        float acc = b_fc[o];
        const float4* wv = (const float4*)(W_fc + o * HDIM);
#pragma unroll 8
        for (int k4 = 0; k4 < HDIM / 4; k4++) {
            float4 w = wv[k4];
            const int k0 = 4 * k4;
            acc = fmaf(__uint_as_float((unsigned)hb[(k0 + 0) * 8 + bc]), w.x, acc);
            acc = fmaf(__uint_as_float((unsigned)hb[(k0 + 1) * 8 + bc]), w.y, acc);
            acc = fmaf(__uint_as_float((unsigned)hb[(k0 + 2) * 8 + bc]), w.z, acc);
            acc = fmaf(__uint_as_float((unsigned)hb[(k0 + 3) * 8 + bc]), w.w, acc);
        }
        sl[o * BATCH + b] = acc;
    }
    __syncthreads();
    if (t < BATCH) {
        float l0 = sl[t], l1 = sl[BATCH + t], l2 = sl[2 * BATCH + t];
        float l3 = sl[3 * BATCH + t], l4 = sl[4 * BATCH + t];
        float m = fmaxf(fmaxf(fmaxf(l0, l1), fmaxf(l2, l3)), l4);
        float e0 = __expf(l0 - m), e1 = __expf(l1 - m), e2 = __expf(l2 - m);
        float e3 = __expf(l3 - m), e4 = __expf(l4 - m);
        float inv = 1.0f / (e0 + e1 + e2 + e3 + e4);
        out[t * ODIM + 0] = e0 * inv;
        out[t * ODIM + 1] = e1 * inv;
        out[t * ODIM + 2] = e2 * inv;
        out[t * ODIM + 3] = e3 * inv;
        out[t * ODIM + 4] = e4 * inv;
    }
}

extern "C" void kernel_launch(void* const* d_in, const int* in_sizes, int n_in,
                              void* d_out, int out_size, void* d_ws, size_t ws_size,
                              hipStream_t stream)
{
    const int*   x    = (const int*)d_in[0];
    const float* emb  = (const float*)d_in[1];
    const float* W_ih = (const float*)d_in[2];
    const float* W_hh = (const float*)d_in[3];
    const float* b_ih = (const float*)d_in[4];
    const float* b_hh = (const float*)d_in[5];
    const float* W_fc = (const float*)d_in[6];
    const float* b_fc = (const float*)d_in[7];
    float* out = (float*)d_out;

    // ws layout: [htag 512 KiB][gates 105 MB (optional)]
    unsigned long long* htag = (unsigned long long*)d_ws;
    const size_t gates_bytes = GATES_FLOATS * sizeof(float);
    float* gates = nullptr;
    if (ws_size >= (size_t)HT_BYTES + gates_bytes)
        gates = (float*)((char*)d_ws + HT_BYTES);

    // reset tags to 0 each launch (step-0 consumers expect tag 0 / h = 0)
    (void)hipMemsetAsync(htag, 0, HT_BYTES, stream);

    (void)hipFuncSetAttribute((const void*)lstm_persist,
                              hipFuncAttributeMaxDynamicSharedMemorySize, LDS_BYTES);
    if (gates) {
        (void)hipFuncSetAttribute((const void*)lstm_pre,
                                  hipFuncAttributeMaxDynamicSharedMemorySize, PRE_LDS_BYTES);
        lstm_pre<<<SEQL * 8, 256, PRE_LDS_BYTES, stream>>>(x, emb, W_ih, gates);
    }

    lstm_persist<<<NWG, TPB, LDS_BYTES, stream>>>(x, emb, W_ih, W_hh, b_ih, b_hh,
                                                  gates, htag);

    lstm_epilogue<<<1, 320, 0, stream>>>(htag, W_fc, b_fc, out);
}

// Round 11
// 1745.968 us; speedup vs baseline: 2.2273x; 1.0255x over previous
//
#include <hip/hip_runtime.h>

// ---------------- problem constants ----------------
#define TPB   256
#define NWG   256
#define SEQL  200
#define BATCH 64
#define EDIM  300
#define HDIM  512
#define ODIM  5
#define NROW  (4*HDIM)   // 2048 gate rows

// ---------------- group decomposition ----------------
#define GROUPS 8      // independent batch groups (group = blockIdx & 7)
#define GCUS   32     // CUs per group (j = blockIdx >> 3)
#define GB     8      // batch rows per group
#define UNITS  16     // h units per CU
#define KSLC   32     // k per kh slice (16 slices)

// ---------------- persist-kernel LDS layout (word offsets) ----------------
// [0..4096)      h tile [512 k][8 b], half-XOR swizzled:
//                phys = 8k + 4*(half ^ ((k>>5)&1)) + (b&3)
// [4096..12864)  ex[64 r][8 b] (r stride 137, b stride 17)
// [12864..15264) embT[300][8] (fallback only)
#define H_WORDS  4096
#define EX_OFF   4096
#define EX_RSTR  137
#define EX_BSTR  17
#define EMB_OFF  (EX_OFF + 64*EX_RSTR)       // 12864
#define LDS_BYTES 83968                      // padded -> 1 wg/CU

// ---------------- tagged h exchange ----------------
// htag[parity][group][4096] : ull = (tag << 32) | f32bits(value)
// value index vi = k*8 + b.  Input for step s: parity s&1, tag == s.
#define HT_GROUP 4096
#define HT_PAR   (GROUPS * HT_GROUP)               // 32768 ull per parity
#define HT_TOTAL (2 * HT_PAR)                      // 65536 ull = 512 KiB
#define HT_BYTES (HT_TOTAL * 8)

// ---------------- precompute-kernel LDS ----------------
#define ESTR 308
#define PRE_LDS_BYTES (BATCH * ESTR * 4)     // 78848 B

#define GATES_FLOATS ((size_t)SEQL * NROW * BATCH)   // 104.9 MB

__device__ __forceinline__ float fast_sigmoid(float x) {
    return 1.0f / (1.0f + __expf(-x));
}
__device__ __forceinline__ float fast_tanh(float x) {
    return 2.0f / (1.0f + __expf(-2.0f * x)) - 1.0f;
}

// ============================================================================
// Precompute: gates[s][octet g][row][8] = (x_s @ W_ih^T) for batch 8g..8g+7
// ============================================================================
extern "C" __global__ void __launch_bounds__(256, 1)
lstm_pre(const int* __restrict__ x, const float* __restrict__ emb,
         const float* __restrict__ W_ih, float* __restrict__ gates)
{
    extern __shared__ float embs[];
    const int tid = threadIdx.x;
    const int s   = blockIdx.x >> 3;
    const int rb  = blockIdx.x & 7;

    for (int i = tid; i < BATCH * 75; i += 256) {
        int b = i / 75, jj = i - b * 75;
        int row = x[b * SEQL + s];
        float4 v = ((const float4*)(emb + (size_t)row * EDIM))[jj];
        *(float4*)&embs[b * ESTR + 4 * jj] = v;
    }
    __syncthreads();

    const int bi = tid >> 5;      // batch octet = group
    const int ri = tid & 31;
    const int row0 = rb * 256 + ri * 8;
    const float* wp = W_ih + (size_t)row0 * EDIM;

    float acc[8][8];
#pragma unroll
    for (int a = 0; a < 8; a++)
#pragma unroll
        for (int b = 0; b < 8; b++) acc[a][b] = 0.0f;

    for (int t2 = 0; t2 < 75; t2++) {
        float4 w[8], e[8];
#pragma unroll
        for (int rr = 0; rr < 8; rr++)
            w[rr] = *(const float4*)(wp + rr * EDIM + 4 * t2);
#pragma unroll
        for (int bb = 0; bb < 8; bb++)
            e[bb] = *(const float4*)&embs[(bi * 8 + bb) * ESTR + 4 * t2];
#pragma unroll
        for (int rr = 0; rr < 8; rr++)
#pragma unroll
            for (int bb = 0; bb < 8; bb++) {
                acc[rr][bb] = fmaf(w[rr].x, e[bb].x, acc[rr][bb]);
                acc[rr][bb] = fmaf(w[rr].y, e[bb].y, acc[rr][bb]);
                acc[rr][bb] = fmaf(w[rr].z, e[bb].z, acc[rr][bb]);
                acc[rr][bb] = fmaf(w[rr].w, e[bb].w, acc[rr][bb]);
            }
    }
#pragma unroll
    for (int rr = 0; rr < 8; rr++) {
        float* dst = gates + (((size_t)s * 8 + bi) * NROW + row0 + rr) * 8;
        *(float4*)dst       = make_float4(acc[rr][0], acc[rr][1], acc[rr][2], acc[rr][3]);
        *(float4*)(dst + 4) = make_float4(acc[rr][4], acc[rr][5], acc[rr][6], acc[rr][7]);
    }
}

// ============================================================================
// Persistent LSTM, 8 independent batch-groups of 32 CUs. Tagged h exchange
// (8B {tag,value} words, parity double-buffered, no fences). Round-11:
// w4 PINNED in VGPRs via opaque asm (r10: VGPR=152 < working set -> regalloc
// re-loaded W_hh every step from L2/L3, invisible in FETCH/WRITE); poll
// restructured to per-u granularity (peak 8 live poll regs, not 32);
// gates loads non-temporal (keep L2 clean).
// ============================================================================
extern "C" __global__ void __launch_bounds__(TPB, 1)
lstm_persist(const int* __restrict__ x, const float* __restrict__ emb,
             const float* __restrict__ W_ih, const float* __restrict__ W_hh,
             const float* __restrict__ b_ih, const float* __restrict__ b_hh,
             const float* __restrict__ gates,      // may be null
             unsigned long long* __restrict__ htag) // [2][8][4096] tagged h
{
    extern __shared__ float lds[];
    const int tid = threadIdx.x;
    const int g   = blockIdx.x & 7;
    const int j   = blockIdx.x >> 3;
    const bool pre = (gates != nullptr);

    const int rq = tid & 15;      // rows 4rq..4rq+3 (r = gate*16+u)
    const int kh = tid >> 4;      // k in [32kh, 32kh+32)

    // ---- W_hh slice -> 128 VGPRs (static indexing only; rule #20) ----
    float4 w4[4][8];
#pragma unroll
    for (int p = 0; p < 4; p++) {
        const int r = 4 * rq + p;
        const size_t R = (size_t)((r >> 4) * HDIM + UNITS * j + (r & 15));
        const float* wp = W_hh + R * HDIM + KSLC * kh;
#pragma unroll
        for (int kq = 0; kq < 8; kq++) w4[p][kq] = *(const float4*)(wp + 4 * kq);
    }
    // Opaque pin: w4 values now "originate" from asm -> not rematerializable
    // by re-loading W_hh inside the step loop (r10 hidden cost).
#pragma unroll
    for (int p = 0; p < 4; p++)
#pragma unroll
        for (int kq = 0; kq < 8; kq++)
            asm volatile("" : "+v"(w4[p][kq].x), "+v"(w4[p][kq].y),
                             "+v"(w4[p][kq].z), "+v"(w4[p][kq].w));

    // cell role: tid<128 owns (u = tid>>3, b = tid&7)
    const int cu = tid >> 3;
    const int cbb = tid & 7;
    float bias4[4];
#pragma unroll
    for (int gt = 0; gt < 4; gt++) {
        int R = gt * HDIM + UNITS * j + (cu & 15);
        bias4[gt] = b_ih[R] + b_hh[R];
    }
    float c_reg = 0.0f;

    const int sw = 4 * (kh & 1);  // pass-B half-XOR select

    unsigned long long* const T0 = htag + (size_t)g * HT_GROUP;            // parity 0
    unsigned long long* const T1 = htag + HT_PAR + (size_t)g * HT_GROUP;   // parity 1

    __syncthreads();

    for (int s = 0; s < SEQL; s++) {
        const unsigned long long* Tin = (s & 1) ? T1 : T0;
        unsigned long long*       Tout = (s & 1) ? T0 : T1;

        // ---- (0) prefetch input-proj gates (non-temporal: single-use stream) ----
        float gp[4] = {0.f, 0.f, 0.f, 0.f};
        if (pre && tid < 128) {
            const float* gbase = gates + (((size_t)s * 8 + g) * NROW + UNITS * j) * 8;
#pragma unroll
            for (int gt = 0; gt < 4; gt++)
                gp[gt] = __builtin_nontemporal_load(gbase + (size_t)gt * (HDIM * 8) + tid);
        }

        float acc[4][8];
#pragma unroll
        for (int p = 0; p < 4; p++)
#pragma unroll
            for (int b = 0; b < 8; b++) acc[p][b] = 0.f;

        // ---- (1) fallback pass A (cold path; pre-path skips) ----
        if (!pre) {
            for (int i = tid; i < EDIM * GB; i += TPB) {
                int e = i >> 3, b = i & 7;
                int row = x[(GB * g + b) * SEQL + s];
                lds[EMB_OFF + e * 8 + b] = emb[(size_t)row * EDIM + e];
            }
            __syncthreads();
            if (kh < 15) {
                for (int e = 20 * kh; e < 20 * kh + 20; e++) {
                    float4 e0 = *(const float4*)&lds[EMB_OFF + e * 8];
                    float4 e1 = *(const float4*)&lds[EMB_OFF + e * 8 + 4];
#pragma unroll
                    for (int p = 0; p < 4; p++) {
                        const int r = 4 * rq + p;
                        const size_t R = (size_t)((r >> 4) * HDIM + UNITS * j + (r & 15));
                        float wc = W_ih[R * EDIM + e];
                        acc[p][0] = fmaf(wc, e0.x, acc[p][0]);
                        acc[p][1] = fmaf(wc, e0.y, acc[p][1]);
                        acc[p][2] = fmaf(wc, e0.z, acc[p][2]);
                        acc[p][3] = fmaf(wc, e0.w, acc[p][3]);
                        acc[p][4] = fmaf(wc, e1.x, acc[p][4]);
                        acc[p][5] = fmaf(wc, e1.y, acc[p][5]);
                        acc[p][6] = fmaf(wc, e1.z, acc[p][6]);
                        acc[p][7] = fmaf(wc, e1.w, acc[p][7]);
                    }
                }
            }
            __syncthreads();   // embT reads done before h-tile staging below
        }

        // ---- (2) poll-stage tagged h tile, PER-U (low register pressure) ----
        // u-chunk: 4 words {vi = 4*tid + 1024u + q}. Once a word's tag == s its
        // value is final for this parity (tag+value read as one atomic 8B).
        {
            const unsigned tag = (unsigned)s;
#pragma unroll
            for (int u = 0; u < 4; u++) {
                const int vi = 4 * tid + 1024 * u;
                unsigned long long d0, d1, d2, d3;
                for (;;) {
                    d0 = __hip_atomic_load(Tin + vi + 0, __ATOMIC_RELAXED, __HIP_MEMORY_SCOPE_AGENT);
                    d1 = __hip_atomic_load(Tin + vi + 1, __ATOMIC_RELAXED, __HIP_MEMORY_SCOPE_AGENT);
                    d2 = __hip_atomic_load(Tin + vi + 2, __ATOMIC_RELAXED, __HIP_MEMORY_SCOPE_AGENT);
                    d3 = __hip_atomic_load(Tin + vi + 3, __ATOMIC_RELAXED, __HIP_MEMORY_SCOPE_AGENT);
                    if ((unsigned)(d0 >> 32) == tag && (unsigned)(d1 >> 32) == tag &&
                        (unsigned)(d2 >> 32) == tag && (unsigned)(d3 >> 32) == tag)
                        break;
                    __builtin_amdgcn_s_sleep(1);
                }
                float4 hv;
                hv.x = __uint_as_float((unsigned)d0);
                hv.y = __uint_as_float((unsigned)d1);
                hv.z = __uint_as_float((unsigned)d2);
                hv.w = __uint_as_float((unsigned)d3);
                const int blk = tid + 256 * u;
                const int k = blk >> 1, hf = blk & 1;
                const int phys = 8 * k + 4 * (hf ^ ((k >> 5) & 1));
                *(float4*)&lds[phys] = hv;
            }
        }
        __syncthreads();

        // ---- (3) pass B: fully static unroll; W_hh regs x h LDS ----
#pragma unroll
        for (int kq = 0; kq < 8; kq++) {
#pragma unroll
            for (int ki = 0; ki < 4; ki++) {
                const int kb = 256 * kh + 8 * (4 * kq + ki);
                float4 h0 = *(const float4*)&lds[kb + sw];        // b 0-3
                float4 h1 = *(const float4*)&lds[kb + (4 - sw)];  // b 4-7
#pragma unroll
                for (int p = 0; p < 4; p++) {
                    const float4 wv = w4[p][kq];
                    const float wc = ki == 0 ? wv.x : ki == 1 ? wv.y
                                   : ki == 2 ? wv.z : wv.w;
                    acc[p][0] = fmaf(wc, h0.x, acc[p][0]);
                    acc[p][1] = fmaf(wc, h0.y, acc[p][1]);
                    acc[p][2] = fmaf(wc, h0.z, acc[p][2]);
                    acc[p][3] = fmaf(wc, h0.w, acc[p][3]);
                    acc[p][4] = fmaf(wc, h1.x, acc[p][4]);
                    acc[p][5] = fmaf(wc, h1.y, acc[p][5]);
                    acc[p][6] = fmaf(wc, h1.z, acc[p][6]);
                    acc[p][7] = fmaf(wc, h1.w, acc[p][7]);
                }
            }
        }
        __syncthreads();   // h-tile readers done; ex region reusable

        // ---- (4) exchange k-partials: ex[r][b][kh], ~2-way banks ----
#pragma unroll
        for (int p = 0; p < 4; p++) {
            const int base = EX_OFF + (4 * rq + p) * EX_RSTR + kh;
#pragma unroll
            for (int b = 0; b < 8; b++)
                lds[base + b * EX_BSTR] = acc[p][b];
        }
        __syncthreads();

        // ---- (5) cell update + tagged store (tid<128 owns (u, b)) ----
        if (tid < 128) {
            float gs[4];
#pragma unroll
            for (int gt = 0; gt < 4; gt++) {
                float sum = bias4[gt] + gp[gt];
                const int base = EX_OFF + (gt * 16 + cu) * EX_RSTR + cbb * EX_BSTR;
#pragma unroll
                for (int kk = 0; kk < 16; kk++) sum += lds[base + kk];
                gs[gt] = sum;
            }
            float iv = fast_sigmoid(gs[0]);
            float fv = fast_sigmoid(gs[1]);
            float gv = fast_tanh(gs[2]);
            float ov = fast_sigmoid(gs[3]);
            c_reg = fv * c_reg + iv * gv;
            float hv = ov * fast_tanh(c_reg);
            // vi = (16j+u)*8 + b = 128j + tid ; tag = s+1
            unsigned long long wword =
                ((unsigned long long)(unsigned)(s + 1) << 32) |
                (unsigned long long)__float_as_uint(hv);
            __hip_atomic_store(Tout + 128 * j + tid, wword,
                               __ATOMIC_RELAXED, __HIP_MEMORY_SCOPE_AGENT);
        }
        // no trailing barrier: next step's h-tile LDS writes are disjoint from
        // ex; ex rewrite at s+1 is behind two __syncthreads.
    }
}

// FC head + softmax. Final h: parity SEQL&1 = 0, value = lo32 of tagged word.
extern "C" __global__ void __launch_bounds__(320)
lstm_epilogue(const unsigned long long* __restrict__ htag,
              const float* __restrict__ W_fc, const float* __restrict__ b_fc,
              float* __restrict__ out)
{
    __shared__ float sl[ODIM * BATCH];
    const int t = threadIdx.x;
    {
        int o = t / BATCH, b = t - o * BATCH;
        const unsigned long long* hb = htag + (size_t)(b >> 3) * HT_GROUP;
        const int bc = b & 7;
        float acc = b_fc[o];
        const float4* wv = (const float4*)(W_fc + o * HDIM);
#pragma unroll 8
        for (int k4 = 0; k4 < HDIM / 4; k4++) {
            float4 w = wv[k4];
            const int k0 = 4 * k4;
            acc = fmaf(__uint_as_float((unsigned)hb[(k0 + 0) * 8 + bc]), w.x, acc);
            acc = fmaf(__uint_as_float((unsigned)hb[(k0 + 1) * 8 + bc]), w.y, acc);
            acc = fmaf(__uint_as_float((unsigned)hb[(k0 + 2) * 8 + bc]), w.z, acc);
            acc = fmaf(__uint_as_float((unsigned)hb[(k0 + 3) * 8 + bc]), w.w, acc);
        }
        sl[o * BATCH + b] = acc;
    }
    __syncthreads();
    if (t < BATCH) {
        float l0 = sl[t], l1 = sl[BATCH + t], l2 = sl[2 * BATCH + t];
        float l3 = sl[3 * BATCH + t], l4 = sl[4 * BATCH + t];
        float m = fmaxf(fmaxf(fmaxf(l0, l1), fmaxf(l2, l3)), l4);
        float e0 = __expf(l0 - m), e1 = __expf(l1 - m), e2 = __expf(l2 - m);
        float e3 = __expf(l3 - m), e4 = __expf(l4 - m);
        float inv = 1.0f / (e0 + e1 + e2 + e3 + e4);
        out[t * ODIM + 0] = e0 * inv;
        out[t * ODIM + 1] = e1 * inv;
        out[t * ODIM + 2] = e2 * inv;
        out[t * ODIM + 3] = e3 * inv;
        out[t * ODIM + 4] = e4 * inv;
    }
}

extern "C" void kernel_launch(void* const* d_in, const int* in_sizes, int n_in,
                              void* d_out, int out_size, void* d_ws, size_t ws_size,
                              hipStream_t stream)
{
    const int*   x    = (const int*)d_in[0];
    const float* emb  = (const float*)d_in[1];
    const float* W_ih = (const float*)d_in[2];
    const float* W_hh = (const float*)d_in[3];
    const float* b_ih = (const float*)d_in[4];
    const float* b_hh = (const float*)d_in[5];
    const float* W_fc = (const float*)d_in[6];
    const float* b_fc = (const float*)d_in[7];
    float* out = (float*)d_out;

    // ws layout: [htag 512 KiB][gates 105 MB (optional)]
    unsigned long long* htag = (unsigned long long*)d_ws;
    const size_t gates_bytes = GATES_FLOATS * sizeof(float);
    float* gates = nullptr;
    if (ws_size >= (size_t)HT_BYTES + gates_bytes)
        gates = (float*)((char*)d_ws + HT_BYTES);

    // reset tags to 0 each launch (step-0 consumers expect tag 0 / h = 0)
    (void)hipMemsetAsync(htag, 0, HT_BYTES, stream);

    (void)hipFuncSetAttribute((const void*)lstm_persist,
                              hipFuncAttributeMaxDynamicSharedMemorySize, LDS_BYTES);
    if (gates) {
        (void)hipFuncSetAttribute((const void*)lstm_pre,
                                  hipFuncAttributeMaxDynamicSharedMemorySize, PRE_LDS_BYTES);
        lstm_pre<<<SEQL * 8, 256, PRE_LDS_BYTES, stream>>>(x, emb, W_ih, gates);
    }

    lstm_persist<<<NWG, TPB, LDS_BYTES, stream>>>(x, emb, W_ih, W_hh, b_ih, b_hh,
                                                  gates, htag);

    lstm_epilogue<<<1, 320, 0, stream>>>(htag, W_fc, b_fc, out);
}

// Round 12
// 1732.222 us; speedup vs baseline: 2.2450x; 1.0079x over previous
//
#include <hip/hip_runtime.h>

// ---------------- problem constants ----------------
#define TPB   256
#define NWG   512
#define SEQL  200
#define BATCH 64
#define EDIM  300
#define HDIM  512
#define ODIM  5
#define NROW  (4*HDIM)   // 2048 gate rows

// ---------------- group decomposition ----------------
#define GROUPS 16     // independent batch groups (group = blockIdx & 15)
#define GCUS   32     // blocks per group (j = blockIdx >> 4)
#define GB     4      // batch rows per group
#define UNITS  16     // h units per block
#define KSLC   32     // k per kh slice (16 slices)

// ---------------- persist-kernel LDS layout (word offsets) ----------------
// [0..2048)     h tile [512 k][4 b]; phys = (4k ^ (((k>>5)&3)<<2)) + b
//               -> pass-B float4 reads conflict-free (4 kh-lanes hit
//                  disjoint bank quads); region [512w,512w+512) is
//                  wave-w-exclusive (write & read) -> no stage barrier.
// [2048..6464)  ex[64 r][4 b][16 kh]: addr = 2048 + r*69 + b*17 + kh
// [6464..7664)  embT[300][4] (fallback only)
#define EX_OFF   2048
#define EX_RSTR  69
#define EX_BSTR  17
#define EMB_OFF  (EX_OFF + 64*EX_RSTR)       // 6464
#define LDS_BYTES 56320                      // 55 KiB: 2/CU fit, 3 don't

// ---------------- tagged h exchange ----------------
// htag[parity][group][2048] : ull = (tag << 32) | f32bits(value)
// value index vi = k*4 + b. Input for step s: parity s&1, tag == s.
#define HT_GROUP 2048
#define HT_PAR   (GROUPS * HT_GROUP)               // 32768 ull per parity
#define HT_BYTES (2 * HT_PAR * 8)                  // 512 KiB

// ---------------- precompute-kernel LDS ----------------
#define ESTR 308
#define PRE_LDS_BYTES (BATCH * ESTR * 4)     // 78848 B

#define GATES_FLOATS ((size_t)SEQL * NROW * BATCH)   // 104.9 MB

__device__ __forceinline__ float fast_sigmoid(float x) {
    return 1.0f / (1.0f + __expf(-x));
}
__device__ __forceinline__ float fast_tanh(float x) {
    return 2.0f / (1.0f + __expf(-2.0f * x)) - 1.0f;
}

// ============================================================================
// Precompute: gates[s][group][row][4] = (x_s @ W_ih^T) for batch 4g..4g+3.
// Each thread's store: 2 x 128B fully contiguous (one per group).
// ============================================================================
extern "C" __global__ void __launch_bounds__(256, 1)
lstm_pre(const int* __restrict__ x, const float* __restrict__ emb,
         const float* __restrict__ W_ih, float* __restrict__ gates)
{
    extern __shared__ float embs[];
    const int tid = threadIdx.x;
    const int s   = blockIdx.x >> 3;
    const int rb  = blockIdx.x & 7;

    for (int i = tid; i < BATCH * 75; i += 256) {
        int b = i / 75, jj = i - b * 75;
        int row = x[b * SEQL + s];
        float4 v = ((const float4*)(emb + (size_t)row * EDIM))[jj];
        *(float4*)&embs[b * ESTR + 4 * jj] = v;
    }
    __syncthreads();

    const int bi = tid >> 5;      // batch octet (groups 2bi, 2bi+1)
    const int ri = tid & 31;
    const int row0 = rb * 256 + ri * 8;
    const float* wp = W_ih + (size_t)row0 * EDIM;

    float acc[8][8];
#pragma unroll
    for (int a = 0; a < 8; a++)
#pragma unroll
        for (int b = 0; b < 8; b++) acc[a][b] = 0.0f;

    for (int t2 = 0; t2 < 75; t2++) {
        float4 w[8], e[8];
#pragma unroll
        for (int rr = 0; rr < 8; rr++)
            w[rr] = *(const float4*)(wp + rr * EDIM + 4 * t2);
#pragma unroll
        for (int bb = 0; bb < 8; bb++)
            e[bb] = *(const float4*)&embs[(bi * 8 + bb) * ESTR + 4 * t2];
#pragma unroll
        for (int rr = 0; rr < 8; rr++)
#pragma unroll
            for (int bb = 0; bb < 8; bb++) {
                acc[rr][bb] = fmaf(w[rr].x, e[bb].x, acc[rr][bb]);
                acc[rr][bb] = fmaf(w[rr].y, e[bb].y, acc[rr][bb]);
                acc[rr][bb] = fmaf(w[rr].z, e[bb].z, acc[rr][bb]);
                acc[rr][bb] = fmaf(w[rr].w, e[bb].w, acc[rr][bb]);
            }
    }
    // gates word idx: (s*16 + g)*8192 + row*4 + b
    float* dstA = gates + (size_t)(s * GROUPS + 2 * bi)     * 8192 + row0 * 4;
    float* dstB = gates + (size_t)(s * GROUPS + 2 * bi + 1) * 8192 + row0 * 4;
#pragma unroll
    for (int rr = 0; rr < 8; rr++) {
        *(float4*)(dstA + 4 * rr) = make_float4(acc[rr][0], acc[rr][1], acc[rr][2], acc[rr][3]);
        *(float4*)(dstB + 4 * rr) = make_float4(acc[rr][4], acc[rr][5], acc[rr][6], acc[rr][7]);
    }
}

// ============================================================================
// Persistent LSTM, 16 batch-groups x 32 blocks, 2 blocks/CU (TLP fills poll
// stalls). Tagged h exchange (8B {tag,value}, parity dbuf, no fences).
// Wave-local staging: wave w polls+stages only k in [128w,128w+128) -> no
// barrier between staging and pass B; earliest-arrival compute.
// ============================================================================
extern "C" __global__ void __launch_bounds__(TPB, 2)
lstm_persist(const int* __restrict__ x, const float* __restrict__ emb,
             const float* __restrict__ W_ih, const float* __restrict__ W_hh,
             const float* __restrict__ b_ih, const float* __restrict__ b_hh,
             const float* __restrict__ gates,      // may be null
             unsigned long long* __restrict__ htag) // [2][16][2048] tagged h
{
    extern __shared__ float lds[];
    const int tid = threadIdx.x;
    const int g   = blockIdx.x & 15;
    const int j   = blockIdx.x >> 4;        // 0..31
    const bool pre = (gates != nullptr);

    const int rq = tid & 15;      // rows 4rq..4rq+3 (r = gate*16+u)
    const int kh = tid >> 4;      // k in [32kh, 32kh+32)
    const int wv = tid >> 6;      // wave 0..3
    const int ln = tid & 63;      // lane

    // ---- W_hh slice -> 128 VGPRs (static indexing only; rule #20) ----
    float4 w4[4][8];
#pragma unroll
    for (int p = 0; p < 4; p++) {
        const int r = 4 * rq + p;
        const size_t R = (size_t)((r >> 4) * HDIM + UNITS * j + (r & 15));
        const float* wp = W_hh + R * HDIM + KSLC * kh;
#pragma unroll
        for (int kq = 0; kq < 8; kq++) w4[p][kq] = *(const float4*)(wp + 4 * kq);
    }
#pragma unroll
    for (int p = 0; p < 4; p++)
#pragma unroll
        for (int kq = 0; kq < 8; kq++)
            asm volatile("" : "+v"(w4[p][kq].x), "+v"(w4[p][kq].y),
                             "+v"(w4[p][kq].z), "+v"(w4[p][kq].w));

    // cell role: tid<64 owns (u = tid>>2, b = tid&3)
    const int uu = (tid & 63) >> 2;     // in-range for all tid
    const int cb = tid & 3;
    float bias4[4];
#pragma unroll
    for (int gt = 0; gt < 4; gt++) {
        int R = gt * HDIM + UNITS * j + uu;
        bias4[gt] = b_ih[R] + b_hh[R];
    }
    float c_reg = 0.0f;

    const int swz = (kh & 3) << 2;      // pass-B read swizzle

    unsigned long long* const T0 = htag + (size_t)g * HT_GROUP;            // parity 0
    unsigned long long* const T1 = htag + HT_PAR + (size_t)g * HT_GROUP;   // parity 1

    __syncthreads();

    for (int s = 0; s < SEQL; s++) {
        const unsigned long long* Tin = (s & 1) ? T1 : T0;
        unsigned long long*       Tout = (s & 1) ? T0 : T1;

        // ---- (0) prefetch input-proj gates (non-temporal stream) ----
        float gp[4] = {0.f, 0.f, 0.f, 0.f};
        if (pre && tid < 64) {
            const float* gbase = gates + (size_t)(s * GROUPS + g) * 8192 + 64 * j;
#pragma unroll
            for (int gt = 0; gt < 4; gt++)
                gp[gt] = __builtin_nontemporal_load(gbase + gt * 2048 + tid);
        }

        float acc[4][4];
#pragma unroll
        for (int p = 0; p < 4; p++)
#pragma unroll
            for (int b = 0; b < 4; b++) acc[p][b] = 0.f;

        // ---- (1) fallback pass A (cold path; pre-path skips) ----
        if (!pre) {
            for (int i = tid; i < EDIM * GB; i += TPB) {
                int e = i >> 2, b = i & 3;
                int row = x[(GB * g + b) * SEQL + s];
                lds[EMB_OFF + i] = emb[(size_t)row * EDIM + e];
            }
            __syncthreads();
            if (kh < 15) {
                for (int e = 20 * kh; e < 20 * kh + 20; e++) {
                    float4 e0 = *(const float4*)&lds[EMB_OFF + 4 * e];
#pragma unroll
                    for (int p = 0; p < 4; p++) {
                        const int r = 4 * rq + p;
                        const size_t R = (size_t)((r >> 4) * HDIM + UNITS * j + (r & 15));
                        float wc = W_ih[R * EDIM + e];
                        acc[p][0] = fmaf(wc, e0.x, acc[p][0]);
                        acc[p][1] = fmaf(wc, e0.y, acc[p][1]);
                        acc[p][2] = fmaf(wc, e0.z, acc[p][2]);
                        acc[p][3] = fmaf(wc, e0.w, acc[p][3]);
                    }
                }
            }
            __syncthreads();
        }

        // ---- (2) WAVE-LOCAL poll+stage: rows k = 128*wv + {0,64} + ln ----
        {
            const unsigned tag = (unsigned)s;
#pragma unroll
            for (int rr = 0; rr < 2; rr++) {
                const int k = 128 * wv + 64 * rr + ln;
                const int vi = 4 * k;
                unsigned long long d0, d1, d2, d3;
                for (;;) {
                    d0 = __hip_atomic_load(Tin + vi + 0, __ATOMIC_RELAXED, __HIP_MEMORY_SCOPE_AGENT);
                    d1 = __hip_atomic_load(Tin + vi + 1, __ATOMIC_RELAXED, __HIP_MEMORY_SCOPE_AGENT);
                    d2 = __hip_atomic_load(Tin + vi + 2, __ATOMIC_RELAXED, __HIP_MEMORY_SCOPE_AGENT);
                    d3 = __hip_atomic_load(Tin + vi + 3, __ATOMIC_RELAXED, __HIP_MEMORY_SCOPE_AGENT);
                    if ((unsigned)(d0 >> 32) == tag && (unsigned)(d1 >> 32) == tag &&
                        (unsigned)(d2 >> 32) == tag && (unsigned)(d3 >> 32) == tag)
                        break;
                    __builtin_amdgcn_s_sleep(1);
                }
                const int phys = (4 * k) ^ (((k >> 5) & 3) << 2);
                float4 hv;
                hv.x = __uint_as_float((unsigned)d0);
                hv.y = __uint_as_float((unsigned)d1);
                hv.z = __uint_as_float((unsigned)d2);
                hv.w = __uint_as_float((unsigned)d3);
                *(float4*)&lds[phys] = hv;
            }
        }
        // wave-local RAW through LDS: in-order per wave; fence stops compiler
        // from hoisting pass-B reads above the staging writes.
        asm volatile("" ::: "memory");

        // ---- (3) pass B: W_hh regs x h LDS (conflict-free reads) ----
#pragma unroll
        for (int kq = 0; kq < 8; kq++) {
#pragma unroll
            for (int ki = 0; ki < 4; ki++) {
                const int kidx = 4 * kq + ki;
                const float4 h0 = *(const float4*)&lds[128 * kh + ((4 * kidx) ^ swz)];
#pragma unroll
                for (int p = 0; p < 4; p++) {
                    const float4 wvv = w4[p][kq];
                    const float wc = ki == 0 ? wvv.x : ki == 1 ? wvv.y
                                   : ki == 2 ? wvv.z : wvv.w;
                    acc[p][0] = fmaf(wc, h0.x, acc[p][0]);
                    acc[p][1] = fmaf(wc, h0.y, acc[p][1]);
                    acc[p][2] = fmaf(wc, h0.z, acc[p][2]);
                    acc[p][3] = fmaf(wc, h0.w, acc[p][3]);
                }
            }
        }

        // ---- (4) exchange k-partials: ex[r][b][kh] ----
#pragma unroll
        for (int p = 0; p < 4; p++) {
            const int base = EX_OFF + (4 * rq + p) * EX_RSTR + kh;
#pragma unroll
            for (int b = 0; b < 4; b++)
                lds[base + b * EX_BSTR] = acc[p][b];
        }
        __syncthreads();   // B1: all ex writes visible to cell readers

        // ---- (5) cell update + tagged store (tid<64 owns (u, b)) ----
        if (tid < 64) {
            float gs[4];
#pragma unroll
            for (int gt = 0; gt < 4; gt++) {
                float sum = bias4[gt] + gp[gt];
                const int base = EX_OFF + (gt * 16 + uu) * EX_RSTR + cb * EX_BSTR;
#pragma unroll
                for (int kk = 0; kk < 16; kk++) sum += lds[base + kk];
                gs[gt] = sum;
            }
            float iv = fast_sigmoid(gs[0]);
            float fv = fast_sigmoid(gs[1]);
            float gv = fast_tanh(gs[2]);
            float ov = fast_sigmoid(gs[3]);
            c_reg = fv * c_reg + iv * gv;
            float hv = ov * fast_tanh(c_reg);
            // vi = (16j+u)*4 + b = 64j + tid ; tag = s+1
            unsigned long long wword =
                ((unsigned long long)(unsigned)(s + 1) << 32) |
                (unsigned long long)__float_as_uint(hv);
            __hip_atomic_store(Tout + 64 * j + tid, wword,
                               __ATOMIC_RELAXED, __HIP_MEMORY_SCOPE_AGENT);
        }
        __syncthreads();   // B2: cell reads done before next step's ex writes
    }
}

// FC head + softmax. Final h: parity 0 (SEQL even); value = lo32.
extern "C" __global__ void __launch_bounds__(320)
lstm_epilogue(const unsigned long long* __restrict__ htag,
              const float* __restrict__ W_fc, const float* __restrict__ b_fc,
              float* __restrict__ out)
{
    __shared__ float sl[ODIM * BATCH];
    const int t = threadIdx.x;
    {
        int o = t / BATCH, b = t - o * BATCH;
        const unsigned long long* hb = htag + (size_t)(b >> 2) * HT_GROUP;
        const int bc = b & 3;
        float acc = b_fc[o];
        const float4* wv = (const float4*)(W_fc + o * HDIM);
#pragma unroll 8
        for (int k4 = 0; k4 < HDIM / 4; k4++) {
            float4 w = wv[k4];
            const int k0 = 4 * k4;
            acc = fmaf(__uint_as_float((unsigned)hb[(k0 + 0) * 4 + bc]), w.x, acc);
            acc = fmaf(__uint_as_float((unsigned)hb[(k0 + 1) * 4 + bc]), w.y, acc);
            acc = fmaf(__uint_as_float((unsigned)hb[(k0 + 2) * 4 + bc]), w.z, acc);
            acc = fmaf(__uint_as_float((unsigned)hb[(k0 + 3) * 4 + bc]), w.w, acc);
        }
        sl[o * BATCH + b] = acc;
    }
    __syncthreads();
    if (t < BATCH) {
        float l0 = sl[t], l1 = sl[BATCH + t], l2 = sl[2 * BATCH + t];
        float l3 = sl[3 * BATCH + t], l4 = sl[4 * BATCH + t];
        float m = fmaxf(fmaxf(fmaxf(l0, l1), fmaxf(l2, l3)), l4);
        float e0 = __expf(l0 - m), e1 = __expf(l1 - m), e2 = __expf(l2 - m);
        float e3 = __expf(l3 - m), e4 = __expf(l4 - m);
        float inv = 1.0f / (e0 + e1 + e2 + e3 + e4);
        out[t * ODIM + 0] = e0 * inv;
        out[t * ODIM + 1] = e1 * inv;
        out[t * ODIM + 2] = e2 * inv;
        out[t * ODIM + 3] = e3 * inv;
        out[t * ODIM + 4] = e4 * inv;
    }
}

extern "C" void kernel_launch(void* const* d_in, const int* in_sizes, int n_in,
                              void* d_out, int out_size, void* d_ws, size_t ws_size,
                              hipStream_t stream)
{
    const int*   x    = (const int*)d_in[0];
    const float* emb  = (const float*)d_in[1];
    const float* W_ih = (const float*)d_in[2];
    const float* W_hh = (const float*)d_in[3];
    const float* b_ih = (const float*)d_in[4];
    const float* b_hh = (const float*)d_in[5];
    const float* W_fc = (const float*)d_in[6];
    const float* b_fc = (const float*)d_in[7];
    float* out = (float*)d_out;

    // ws layout: [htag 512 KiB][gates 105 MB (optional)]
    unsigned long long* htag = (unsigned long long*)d_ws;
    const size_t gates_bytes = GATES_FLOATS * sizeof(float);
    float* gates = nullptr;
    if (ws_size >= (size_t)HT_BYTES + gates_bytes)
        gates = (float*)((char*)d_ws + HT_BYTES);

    // reset tags each launch (step-0 consumers expect tag 0 / h = 0)
    (void)hipMemsetAsync(htag, 0, HT_BYTES, stream);

    (void)hipFuncSetAttribute((const void*)lstm_persist,
                              hipFuncAttributeMaxDynamicSharedMemorySize, LDS_BYTES);
    if (gates) {
        (void)hipFuncSetAttribute((const void*)lstm_pre,
                                  hipFuncAttributeMaxDynamicSharedMemorySize, PRE_LDS_BYTES);
        lstm_pre<<<SEQL * 8, 256, PRE_LDS_BYTES, stream>>>(x, emb, W_ih, gates);
    }

    lstm_persist<<<NWG, TPB, LDS_BYTES, stream>>>(x, emb, W_ih, W_hh, b_ih, b_hh,
                                                  gates, htag);

    lstm_epilogue<<<1, 320, 0, stream>>>(htag, W_fc, b_fc, out);
}